// Round 7
// baseline (232.178 us; speedup 1.0000x reference)
//
#include <hip/hip_runtime.h>
#include <math.h>

#define P_ 32
#define G_ 256
#define NV 6890
#define M_ (2 * NV)          // 13780 joint points per sample
#define QUADS (M_ / 4)       // 3445 vertex-quads (exact)
#define NPAIR (P_ * G_)      // 8192
#define NB_CC 512            // crosscov blocks; stats blocks appended after

typedef float v2f __attribute__((ext_vector_type(2)));
__device__ inline v2f v2(float a, float b) { v2f r; r.x = a; r.y = b; return r; }
__device__ inline v2f vsplat(float a) { v2f r; r.x = a; r.y = a; return r; }
__device__ inline v2f vfma(v2f a, v2f b, v2f c) { return __builtin_elementwise_fma(a, b, c); }

// ---------------- workspace layout ----------------
struct WS {
    float mu_p[P_][3];
    float var_p[P_];
    float mu_g[G_][3];
    float At[NPAIR][12];     // A = scale*R (9) then t (3); pair = g*32 + p
    float Kmat[NPAIR][9];    // cross-covariance (pre mean-subtraction)
    float pair_err[NPAIR];   // mean v2v error per pair
};

// ---------------- block reduction (valid on thread 0) ----------------
__device__ inline double block_reduce(double v, double* smem) {
#pragma unroll
    for (int off = 32; off > 0; off >>= 1) v += __shfl_down(v, off, 64);
    int wid  = threadIdx.x >> 6;
    int lane = threadIdx.x & 63;
    __syncthreads();
    if (lane == 0) smem[wid] = v;
    __syncthreads();
    double r = 0.0;
    if (threadIdx.x == 0) {
        int nw = blockDim.x >> 6;
        for (int w = 0; w < nw; ++w) r += smem[w];
    }
    return r;
}

// ---------------- kernel 1: packed crosscov (4p x 4g) + fused stats ----------------
// blocks 0..511: ptile(8)*64 + gtile(64), XCD = gtile%8 keeps gt re-reads L2-local.
// blocks 512..799: per-sample stats (0..31 pred mu/var, 32..287 gt mu).
// waves_per_eu(2,2) pins occupancy so the allocator keeps the ~220-reg working
// set in VGPRs (round 6: heuristic shrank to 128 and spilled 19.7 MB to scratch).
__global__ __launch_bounds__(256)
__attribute__((amdgpu_waves_per_eu(2, 2)))
void crosscov_p(const float* __restrict__ pred,
                const float* __restrict__ gt,
                WS* __restrict__ ws) {
    int bx = blockIdx.x;
    int t = threadIdx.x;

    if (bx >= NB_CC) {
        // ---- stats path ----
        int b = bx - NB_CC;
        bool isP = (b < P_);
        const float* base = isP ? pred + (size_t)b * (M_ * 3)
                                : gt + (size_t)(b - P_) * (M_ * 3);
        double sx = 0, sy = 0, sz = 0, sq = 0;
        for (int q = t; q < QUADS; q += 256) {
            const float4* p4 = (const float4*)(base + 12 * (size_t)q);
            float4 a = p4[0], c = p4[1], d = p4[2];
            sx += (double)a.x + (double)a.w + (double)c.z + (double)d.y;
            sy += (double)a.y + (double)c.x + (double)c.w + (double)d.z;
            sz += (double)a.z + (double)c.y + (double)d.x + (double)d.w;
            if (isP) {
                sq += (double)a.x * a.x + (double)a.y * a.y + (double)a.z * a.z +
                      (double)a.w * a.w + (double)c.x * c.x + (double)c.y * c.y +
                      (double)c.z * c.z + (double)c.w * c.w + (double)d.x * d.x +
                      (double)d.y * d.y + (double)d.z * d.z + (double)d.w * d.w;
            }
        }
        __shared__ double smem[4];
        double rx = block_reduce(sx, smem);
        double ry = block_reduce(sy, smem);
        double rz = block_reduce(sz, smem);
        double rq = block_reduce(sq, smem);
        if (t == 0) {
            double mx = rx / M_, my = ry / M_, mz = rz / M_;
            if (isP) {
                ws->mu_p[b][0] = (float)mx;
                ws->mu_p[b][1] = (float)my;
                ws->mu_p[b][2] = (float)mz;
                ws->var_p[b] = (float)(rq - (mx * mx + my * my + mz * mz) * (double)M_);
            } else {
                ws->mu_g[b - P_][0] = (float)mx;
                ws->mu_g[b - P_][1] = (float)my;
                ws->mu_g[b - P_][2] = (float)mz;
            }
        }
        return;
    }

    // ---- crosscov path ----
    int gbase = (bx & 63) * 4;
    int pbase = (bx >> 6) * 4;
    const float* pb[4];
    const float* gb[4];
#pragma unroll
    for (int j = 0; j < 4; ++j) {
        pb[j] = pred + (size_t)(pbase + j) * (M_ * 3);
        gb[j] = gt + (size_t)(gbase + j) * (M_ * 3);
    }

    // acc per pair: (K0,K1) (K3,K4) (K6,K7) packed; (K2,K5) packed; K8 scalar
    v2f a01[16], a34[16], a67[16], a25[16];
    float a8[16];
#pragma unroll
    for (int i = 0; i < 16; ++i) {
        a01[i] = vsplat(0.f); a34[i] = vsplat(0.f);
        a67[i] = vsplat(0.f); a25[i] = vsplat(0.f);
        a8[i] = 0.f;
    }

    for (int q = t; q < QUADS; q += 256) {
        float4 P[4][3];
#pragma unroll
        for (int j = 0; j < 4; ++j) {
            const float4* p4 = (const float4*)(pb[j] + 12 * (size_t)q);
            P[j][0] = p4[0]; P[j][1] = p4[1]; P[j][2] = p4[2];
        }
#pragma unroll
        for (int gg = 0; gg < 4; ++gg) {
            const float4* g4 = (const float4*)(gb[gg] + 12 * (size_t)q);
            float4 Ga = g4[0], Gc = g4[1], Gd = g4[2];
            v2f gxy0 = v2(Ga.x, Ga.y), gxy1 = v2(Ga.w, Gc.x);
            v2f gxy2 = v2(Gc.z, Gc.w), gxy3 = v2(Gd.y, Gd.z);
            float gz0 = Ga.z, gz1 = Gc.y, gz2 = Gd.x, gz3 = Gd.w;
#pragma unroll
            for (int pp = 0; pp < 4; ++pp) {
                int i = gg * 4 + pp;
                float4 Pa = P[pp][0], Pc = P[pp][1], Pd = P[pp][2];
                a01[i] = vfma(vsplat(Pa.x), gxy0, a01[i]);
                a34[i] = vfma(vsplat(Pa.y), gxy0, a34[i]);
                a67[i] = vfma(vsplat(Pa.z), gxy0, a67[i]);
                a25[i] = vfma(v2(Pa.x, Pa.y), vsplat(gz0), a25[i]);
                a8[i]  = fmaf(Pa.z, gz0, a8[i]);
                a01[i] = vfma(vsplat(Pa.w), gxy1, a01[i]);
                a34[i] = vfma(vsplat(Pc.x), gxy1, a34[i]);
                a67[i] = vfma(vsplat(Pc.y), gxy1, a67[i]);
                a25[i] = vfma(v2(Pa.w, Pc.x), vsplat(gz1), a25[i]);
                a8[i]  = fmaf(Pc.y, gz1, a8[i]);
                a01[i] = vfma(vsplat(Pc.z), gxy2, a01[i]);
                a34[i] = vfma(vsplat(Pc.w), gxy2, a34[i]);
                a67[i] = vfma(vsplat(Pd.x), gxy2, a67[i]);
                a25[i] = vfma(v2(Pc.z, Pc.w), vsplat(gz2), a25[i]);
                a8[i]  = fmaf(Pd.x, gz2, a8[i]);
                a01[i] = vfma(vsplat(Pd.y), gxy3, a01[i]);
                a34[i] = vfma(vsplat(Pd.z), gxy3, a34[i]);
                a67[i] = vfma(vsplat(Pd.w), gxy3, a67[i]);
                a25[i] = vfma(v2(Pd.y, Pd.z), vsplat(gz3), a25[i]);
                a8[i]  = fmaf(Pd.w, gz3, a8[i]);
            }
        }
    }

    // unpack to K[16][9]
    float K[16][9];
#pragma unroll
    for (int i = 0; i < 16; ++i) {
        K[i][0] = a01[i].x; K[i][1] = a01[i].y; K[i][2] = a25[i].x;
        K[i][3] = a34[i].x; K[i][4] = a34[i].y; K[i][5] = a25[i].y;
        K[i][6] = a67[i].x; K[i][7] = a67[i].y; K[i][8] = a8[i];
    }

    // full-wave butterfly -> every lane holds wave total
#pragma unroll
    for (int i = 0; i < 16; ++i)
#pragma unroll
        for (int j = 0; j < 9; ++j) {
            float v = K[i][j];
            v += __shfl_xor(v, 1);  v += __shfl_xor(v, 2);
            v += __shfl_xor(v, 4);  v += __shfl_xor(v, 8);
            v += __shfl_xor(v, 16); v += __shfl_xor(v, 32);
            K[i][j] = v;
        }
    __shared__ float part[4][144];
    int lane = t & 63, wave = t >> 6;
    if (lane == 0) {
#pragma unroll
        for (int i = 0; i < 16; ++i)
#pragma unroll
            for (int j = 0; j < 9; ++j) part[wave][i * 9 + j] = K[i][j];
    }
    __syncthreads();
    if (t < 144) {
        float s = part[0][t] + part[1][t] + part[2][t] + part[3][t];
        int idx = t / 9, j = t % 9;
        int gg = idx >> 2, pp = idx & 3;
        ws->Kmat[(gbase + gg) * P_ + (pbase + pp)][j] = s;
    }
}

// ---------------- kernel 2: per-pair SVD -> A = scale*R, t ----------------
// block=64 spreads 8192 threads over 128 CUs; Jacobi capped at 8 sweeps
// (cubic convergence: breaks at ~5 via tol), all f64.
__global__ __launch_bounds__(64) void pair_svd(WS* ws) {
    int pair = blockIdx.x * blockDim.x + threadIdx.x;
    if (pair >= NPAIR) return;
    int p = pair & 31;
    int g = pair >> 5;

    double K[3][3];
#pragma unroll
    for (int a = 0; a < 3; ++a)
#pragma unroll
        for (int b = 0; b < 3; ++b) K[a][b] = (double)ws->Kmat[pair][3 * a + b];
    {   // subtract M * mu_p mu_g^T
        double mp[3] = { ws->mu_p[p][0], ws->mu_p[p][1], ws->mu_p[p][2] };
        double mg[3] = { ws->mu_g[g][0], ws->mu_g[g][1], ws->mu_g[g][2] };
#pragma unroll
        for (int a = 0; a < 3; ++a)
#pragma unroll
            for (int b = 0; b < 3; ++b)
                K[a][b] -= (double)M_ * mp[a] * mg[b];
    }

    // S = K^T K (symmetric PSD)
    double S[3][3];
#pragma unroll
    for (int a = 0; a < 3; ++a)
#pragma unroll
        for (int b = 0; b < 3; ++b) {
            double acc = 0.0;
#pragma unroll
            for (int c = 0; c < 3; ++c) acc += K[c][a] * K[c][b];
            S[a][b] = acc;
        }

    // Jacobi eigendecomposition S = V Lambda V^T
    double V[3][3] = { {1, 0, 0}, {0, 1, 0}, {0, 0, 1} };
    double tr = S[0][0] + S[1][1] + S[2][2];
    double tol = 1e-26 * tr * tr + 1e-300;
    const int PP[3] = {0, 0, 1};
    const int QQ[3] = {1, 2, 2};
    for (int sweep = 0; sweep < 8; ++sweep) {
        double off = S[0][1] * S[0][1] + S[0][2] * S[0][2] + S[1][2] * S[1][2];
        if (off <= tol) break;
        for (int r3 = 0; r3 < 3; ++r3) {
            int pq = PP[r3], qq = QQ[r3];
            double apq = S[pq][qq];
            if (apq == 0.0) continue;
            double theta = (S[qq][qq] - S[pq][pq]) / (2.0 * apq);
            double tt = copysign(1.0, theta) / (fabs(theta) + sqrt(theta * theta + 1.0));
            double c = 1.0 / sqrt(tt * tt + 1.0);
            double sj = tt * c;
            for (int r = 0; r < 3; ++r) {
                double srp = S[r][pq], srq = S[r][qq];
                S[r][pq] = c * srp - sj * srq;
                S[r][qq] = sj * srp + c * srq;
            }
            for (int cc = 0; cc < 3; ++cc) {
                double spr = S[pq][cc], sqr = S[qq][cc];
                S[pq][cc] = c * spr - sj * sqr;
                S[qq][cc] = sj * spr + c * sqr;
            }
            for (int r = 0; r < 3; ++r) {
                double vrp = V[r][pq], vrq = V[r][qq];
                V[r][pq] = c * vrp - sj * vrq;
                V[r][qq] = sj * vrp + c * vrq;
            }
        }
    }

    // sort eigenpairs descending
    double lam[3] = { S[0][0], S[1][1], S[2][2] };
    int idx[3] = { 0, 1, 2 };
    if (lam[idx[0]] < lam[idx[1]]) { int tt = idx[0]; idx[0] = idx[1]; idx[1] = tt; }
    if (lam[idx[0]] < lam[idx[2]]) { int tt = idx[0]; idx[0] = idx[2]; idx[2] = tt; }
    if (lam[idx[1]] < lam[idx[2]]) { int tt = idx[1]; idx[1] = idx[2]; idx[2] = tt; }
    double Vs[3][3];
    double sv[3];
#pragma unroll
    for (int i = 0; i < 3; ++i) {
        double l = lam[idx[i]];
        sv[i] = sqrt(l > 0.0 ? l : 0.0);
        for (int r = 0; r < 3; ++r) Vs[r][i] = V[r][idx[i]];
    }

    // U columns: u_i = K v_i / s_i
    double U[3][3];
#pragma unroll
    for (int i = 0; i < 3; ++i) {
        double kx = K[0][0] * Vs[0][i] + K[0][1] * Vs[1][i] + K[0][2] * Vs[2][i];
        double ky = K[1][0] * Vs[0][i] + K[1][1] * Vs[1][i] + K[1][2] * Vs[2][i];
        double kz = K[2][0] * Vs[0][i] + K[2][1] * Vs[1][i] + K[2][2] * Vs[2][i];
        double inv = (sv[i] > 1e-12 * sv[0] && sv[i] > 0.0) ? 1.0 / sv[i] : 0.0;
        U[0][i] = kx * inv; U[1][i] = ky * inv; U[2][i] = kz * inv;
    }
    if (sv[2] <= 1e-12 * sv[0] || sv[0] == 0.0) {
        U[0][2] = U[1][0] * U[2][1] - U[2][0] * U[1][1];
        U[1][2] = U[2][0] * U[0][1] - U[0][0] * U[2][1];
        U[2][2] = U[0][0] * U[1][1] - U[1][0] * U[0][1];
    }

    double detK = K[0][0] * (K[1][1] * K[2][2] - K[1][2] * K[2][1])
                - K[0][1] * (K[1][0] * K[2][2] - K[1][2] * K[2][0])
                + K[0][2] * (K[1][0] * K[2][1] - K[1][1] * K[2][0]);
    double d = (detK >= 0.0) ? 1.0 : -1.0;

    double varp = (double)ws->var_p[p];
    double scale = (sv[0] + sv[1] + d * sv[2]) / varp;

    float A[9];
#pragma unroll
    for (int a = 0; a < 3; ++a)
#pragma unroll
        for (int b = 0; b < 3; ++b) {
            double r = Vs[a][0] * U[b][0] + Vs[a][1] * U[b][1] + d * Vs[a][2] * U[b][2];
            A[3 * a + b] = (float)(scale * r);
        }
    double mp[3] = { ws->mu_p[p][0], ws->mu_p[p][1], ws->mu_p[p][2] };
    double mg[3] = { ws->mu_g[g][0], ws->mu_g[g][1], ws->mu_g[g][2] };
    float tvec[3];
#pragma unroll
    for (int a = 0; a < 3; ++a)
        tvec[a] = (float)(mg[a] - ((double)A[3 * a + 0] * mp[0] + (double)A[3 * a + 1] * mp[1] +
                                   (double)A[3 * a + 2] * mp[2]));

#pragma unroll
    for (int j = 0; j < 9; ++j) ws->At[pair][j] = A[j];
#pragma unroll
    for (int j = 0; j < 3; ++j) ws->At[pair][9 + j] = tvec[j];
}

// ---------------- kernel 3: packed v2v error (2p x 4g) ----------------
// grid: 1024 = ptile(16)*64 + gtile(64); XCD = gtile%8. waves_per_eu(3,3)
// pins VGPR budget at 170 so the 96-reg A working set stays in registers
// (round 6: heuristic shrank to 48 VGPRs and spilled A to scratch).
__global__ __launch_bounds__(256)
__attribute__((amdgpu_waves_per_eu(3, 3)))
void pair_error_p(const float* __restrict__ pred,
                  const float* __restrict__ gt,
                  WS* __restrict__ ws) {
    int bx = blockIdx.x;
    int gbase = (bx & 63) * 4;
    int pbase = (bx >> 6) * 2;
    int t = threadIdx.x;

    v2f a03[8], a14[8], a25v[8], t01[8];
    float a6[8], a7[8], a8v[8], t2[8];
#pragma unroll
    for (int gg = 0; gg < 4; ++gg)
#pragma unroll
        for (int pp = 0; pp < 2; ++pp) {
            int i = gg * 2 + pp;
            const float* At = ws->At[(gbase + gg) * P_ + (pbase + pp)];
            a03[i] = v2(At[0], At[3]);
            a14[i] = v2(At[1], At[4]);
            a25v[i] = v2(At[2], At[5]);
            t01[i] = v2(At[9], At[10]);
            a6[i] = At[6]; a7[i] = At[7]; a8v[i] = At[8]; t2[i] = At[11];
        }

    const float* pb0 = pred + (size_t)pbase * (M_ * 3);
    const float* pb1 = pred + (size_t)(pbase + 1) * (M_ * 3);
    const float* gb[4];
#pragma unroll
    for (int j = 0; j < 4; ++j) gb[j] = gt + (size_t)(gbase + j) * (M_ * 3);

    float acc[8];
#pragma unroll
    for (int i = 0; i < 8; ++i) acc[i] = 0.f;

    for (int q = t; q < QUADS; q += 256) {
        float4 P[2][3];
        {
            const float4* p4 = (const float4*)(pb0 + 12 * (size_t)q);
            P[0][0] = p4[0]; P[0][1] = p4[1]; P[0][2] = p4[2];
            p4 = (const float4*)(pb1 + 12 * (size_t)q);
            P[1][0] = p4[0]; P[1][1] = p4[1]; P[1][2] = p4[2];
        }
#pragma unroll
        for (int gg = 0; gg < 4; ++gg) {
            const float4* g4 = (const float4*)(gb[gg] + 12 * (size_t)q);
            float4 Ga = g4[0], Gc = g4[1], Gd = g4[2];
            v2f gxy[4] = { v2(Ga.x, Ga.y), v2(Ga.w, Gc.x), v2(Gc.z, Gc.w), v2(Gd.y, Gd.z) };
            float gz[4] = { Ga.z, Gc.y, Gd.x, Gd.w };
#pragma unroll
            for (int pp = 0; pp < 2; ++pp) {
                int i = gg * 2 + pp;
                float4 Pa = P[pp][0], Pc = P[pp][1], Pd = P[pp][2];
                float x[4] = { Pa.x, Pa.w, Pc.z, Pd.y };
                float y[4] = { Pa.y, Pc.x, Pc.w, Pd.z };
                float z[4] = { Pa.z, Pc.y, Pd.x, Pd.w };
                float s = 0.f;
#pragma unroll
                for (int k = 0; k < 4; ++k) {
                    v2f dd = vfma(a03[i], vsplat(x[k]),
                             vfma(a14[i], vsplat(y[k]),
                             vfma(a25v[i], vsplat(z[k]), t01[i])));
                    dd = dd - gxy[k];
                    float dz = fmaf(a6[i], x[k], fmaf(a7[i], y[k], fmaf(a8v[i], z[k], t2[i]))) - gz[k];
                    v2f m = dd * dd;
                    s += __builtin_amdgcn_sqrtf(fmaf(dz, dz, m.x + m.y));
                }
                acc[i] += s;
            }
        }
    }

#pragma unroll
    for (int i = 0; i < 8; ++i) {
        float v = acc[i];
        v += __shfl_xor(v, 1);  v += __shfl_xor(v, 2);
        v += __shfl_xor(v, 4);  v += __shfl_xor(v, 8);
        v += __shfl_xor(v, 16); v += __shfl_xor(v, 32);
        acc[i] = v;
    }
    __shared__ float part[4][8];
    int lane = t & 63, wave = t >> 6;
    if (lane == 0) {
#pragma unroll
        for (int i = 0; i < 8; ++i) part[wave][i] = acc[i];
    }
    __syncthreads();
    if (t < 8) {
        float s = part[0][t] + part[1][t] + part[2][t] + part[3][t];
        int gg = t >> 1, pp = t & 1;
        ws->pair_err[(gbase + gg) * P_ + (pbase + pp)] = s / (float)M_;
    }
}

// ---------------- kernel 4: argmin over gallery + write outputs ----------------
__global__ void argmin_out(const WS* __restrict__ ws, float* __restrict__ out) {
    __shared__ float be[8][32];
    __shared__ int   bg[8][32];
    int t = threadIdx.x;
    int p = t & 31, slice = t >> 5;
    float best = 3.4e38f;
    int bi = G_;
    for (int g = slice; g < G_; g += 8) {
        float e = ws->pair_err[g * P_ + p];
        if (e < best) { best = e; bi = g; }
    }
    be[slice][p] = best;
    bg[slice][p] = bi;
    __syncthreads();
    if (t < P_) {
        float b0 = be[0][t];
        int   i0 = bg[0][t];
        for (int s = 1; s < 8; ++s) {
            float e = be[s][t];
            int   i = bg[s][t];
            if (e < b0 || (e == b0 && i < i0)) { b0 = e; i0 = i; }
        }
        out[t] = (float)i0;
        out[P_ + t] = b0;
    }
}

extern "C" void kernel_launch(void* const* d_in, const int* in_sizes, int n_in,
                              void* d_out, int out_size, void* d_ws, size_t ws_size,
                              hipStream_t stream) {
    const float* pred = (const float*)d_in[0];   // (32, 2, 6890, 3)
    const float* gt   = (const float*)d_in[1];   // (256, 2, 6890, 3)
    float* out = (float*)d_out;                  // 64 floats: mapping(32) | min_error(32)
    WS* ws = (WS*)d_ws;                          // ~0.8 MB used

    crosscov_p<<<dim3(NB_CC + P_ + G_), dim3(256), 0, stream>>>(pred, gt, ws);
    pair_svd<<<dim3(NPAIR / 64), dim3(64), 0, stream>>>(ws);
    pair_error_p<<<dim3(16 * 64), dim3(256), 0, stream>>>(pred, gt, ws);
    argmin_out<<<dim3(1), dim3(256), 0, stream>>>(ws, out);
}

// Round 8
// 214.589 us; speedup vs baseline: 1.0820x; 1.0820x over previous
//
#include <hip/hip_runtime.h>
#include <math.h>

#define P_ 32
#define G_ 256
#define NV 6890
#define M_ (2 * NV)          // 13780 joint points per sample
#define QUADS (M_ / 4)       // 3445 vertex-quads (exact)
#define NPAIR (P_ * G_)      // 8192
#define NB_CC 512            // crosscov blocks; stats blocks appended after

// ---------------- workspace layout ----------------
struct WS {
    float mu_p[P_][3];
    float var_p[P_];
    float mu_g[G_][3];
    float At[NPAIR][12];     // A = scale*R (9) then t (3); pair = g*32 + p
    float Kmat[NPAIR][9];    // cross-covariance (pre mean-subtraction)
    float pair_err[NPAIR];   // mean v2v error per pair
};

// ---------------- block reduction (valid on thread 0) ----------------
__device__ inline double block_reduce(double v, double* smem) {
#pragma unroll
    for (int off = 32; off > 0; off >>= 1) v += __shfl_down(v, off, 64);
    int wid  = threadIdx.x >> 6;
    int lane = threadIdx.x & 63;
    __syncthreads();
    if (lane == 0) smem[wid] = v;
    __syncthreads();
    double r = 0.0;
    if (threadIdx.x == 0) {
        int nw = blockDim.x >> 6;
        for (int w = 0; w < nw; ++w) r += smem[w];
    }
    return r;
}

// load one 4-vertex quad (x[4],y[4],z[4]) from AoS via 3 float4 loads
#define LOAD_QUAD(BASE, Q, X, Y, Z)                                     \
    {                                                                   \
        const float4* _p4 = (const float4*)((BASE) + 12 * (size_t)(Q)); \
        float4 _a = _p4[0], _c = _p4[1], _d = _p4[2];                   \
        X[0] = _a.x; X[1] = _a.w; X[2] = _c.z; X[3] = _d.y;             \
        Y[0] = _a.y; Y[1] = _c.x; Y[2] = _c.w; Y[3] = _d.z;             \
        Z[0] = _a.z; Z[1] = _c.y; Z[2] = _d.x; Z[3] = _d.w;             \
    }

// ---------------- kernel 1: scalar crosscov (4p x 4g) + fused stats ----------------
// Round-5-proven config: scalar fmaf, __launch_bounds__(256,2) (no waves_per_eu
// pin — round 7 showed pinning hurts; round 5 measured <=72us with this shape).
// blocks 0..511: ptile(8)*64 + gtile(64), XCD = gtile%8 keeps gt re-reads L2-local.
// blocks 512..799: per-sample stats (0..31 pred mu/var, 32..287 gt mu).
__global__ __launch_bounds__(256, 2) void crosscov_r(const float* __restrict__ pred,
                                                     const float* __restrict__ gt,
                                                     WS* __restrict__ ws) {
    int bx = blockIdx.x;
    int t = threadIdx.x;

    if (bx >= NB_CC) {
        // ---- stats path ----
        int b = bx - NB_CC;
        bool isP = (b < P_);
        const float* base = isP ? pred + (size_t)b * (M_ * 3)
                                : gt + (size_t)(b - P_) * (M_ * 3);
        double sx = 0, sy = 0, sz = 0, sq = 0;
        for (int q = t; q < QUADS; q += 256) {
            const float4* p4 = (const float4*)(base + 12 * (size_t)q);
            float4 a = p4[0], c = p4[1], d = p4[2];
            sx += (double)a.x + (double)a.w + (double)c.z + (double)d.y;
            sy += (double)a.y + (double)c.x + (double)c.w + (double)d.z;
            sz += (double)a.z + (double)c.y + (double)d.x + (double)d.w;
            if (isP) {
                sq += (double)a.x * a.x + (double)a.y * a.y + (double)a.z * a.z +
                      (double)a.w * a.w + (double)c.x * c.x + (double)c.y * c.y +
                      (double)c.z * c.z + (double)c.w * c.w + (double)d.x * d.x +
                      (double)d.y * d.y + (double)d.z * d.z + (double)d.w * d.w;
            }
        }
        __shared__ double smem[4];
        double rx = block_reduce(sx, smem);
        double ry = block_reduce(sy, smem);
        double rz = block_reduce(sz, smem);
        double rq = block_reduce(sq, smem);
        if (t == 0) {
            double mx = rx / M_, my = ry / M_, mz = rz / M_;
            if (isP) {
                ws->mu_p[b][0] = (float)mx;
                ws->mu_p[b][1] = (float)my;
                ws->mu_p[b][2] = (float)mz;
                ws->var_p[b] = (float)(rq - (mx * mx + my * my + mz * mz) * (double)M_);
            } else {
                ws->mu_g[b - P_][0] = (float)mx;
                ws->mu_g[b - P_][1] = (float)my;
                ws->mu_g[b - P_][2] = (float)mz;
            }
        }
        return;
    }

    // ---- crosscov path ----
    int gbase = (bx & 63) * 4;
    int pbase = (bx >> 6) * 4;
    const float* pb[4];
    const float* gb[4];
#pragma unroll
    for (int j = 0; j < 4; ++j) {
        pb[j] = pred + (size_t)(pbase + j) * (M_ * 3);
        gb[j] = gt + (size_t)(gbase + j) * (M_ * 3);
    }

    float acc[16][9];
#pragma unroll
    for (int q = 0; q < 16; ++q)
#pragma unroll
        for (int j = 0; j < 9; ++j) acc[q][j] = 0.f;

    for (int q = t; q < QUADS; q += 256) {
        float px[4][4], py[4][4], pz[4][4];
#pragma unroll
        for (int j = 0; j < 4; ++j) LOAD_QUAD(pb[j], q, px[j], py[j], pz[j]);
#pragma unroll
        for (int gg = 0; gg < 4; ++gg) {
            float gx[4], gy[4], gz[4];
            LOAD_QUAD(gb[gg], q, gx, gy, gz);
#pragma unroll
            for (int pp = 0; pp < 4; ++pp) {
                float* a = acc[gg * 4 + pp];
#pragma unroll
                for (int k = 0; k < 4; ++k) {
                    a[0] = fmaf(px[pp][k], gx[k], a[0]);
                    a[1] = fmaf(px[pp][k], gy[k], a[1]);
                    a[2] = fmaf(px[pp][k], gz[k], a[2]);
                    a[3] = fmaf(py[pp][k], gx[k], a[3]);
                    a[4] = fmaf(py[pp][k], gy[k], a[4]);
                    a[5] = fmaf(py[pp][k], gz[k], a[5]);
                    a[6] = fmaf(pz[pp][k], gx[k], a[6]);
                    a[7] = fmaf(pz[pp][k], gy[k], a[7]);
                    a[8] = fmaf(pz[pp][k], gz[k], a[8]);
                }
            }
        }
    }

    // full-wave butterfly -> every lane holds wave total
#pragma unroll
    for (int q = 0; q < 16; ++q)
#pragma unroll
        for (int j = 0; j < 9; ++j) {
            float v = acc[q][j];
            v += __shfl_xor(v, 1);  v += __shfl_xor(v, 2);
            v += __shfl_xor(v, 4);  v += __shfl_xor(v, 8);
            v += __shfl_xor(v, 16); v += __shfl_xor(v, 32);
            acc[q][j] = v;
        }
    __shared__ float part[4][144];
    int lane = t & 63, wave = t >> 6;
    if (lane == 0) {
#pragma unroll
        for (int q = 0; q < 16; ++q)
#pragma unroll
            for (int j = 0; j < 9; ++j) part[wave][q * 9 + j] = acc[q][j];
    }
    __syncthreads();
    if (t < 144) {
        float s = part[0][t] + part[1][t] + part[2][t] + part[3][t];
        int idx = t / 9, j = t % 9;
        int gg = idx >> 2, pp = idx & 3;
        ws->Kmat[(gbase + gg) * P_ + (pbase + pp)][j] = s;
    }
}

// ---------------- kernel 2: per-pair SVD -> A = scale*R, t ----------------
// block=64 over 128 blocks; Jacobi capped at 8 sweeps (tol breaks ~5), f64.
__global__ __launch_bounds__(64) void pair_svd(WS* ws) {
    int pair = blockIdx.x * blockDim.x + threadIdx.x;
    if (pair >= NPAIR) return;
    int p = pair & 31;
    int g = pair >> 5;

    double K[3][3];
#pragma unroll
    for (int a = 0; a < 3; ++a)
#pragma unroll
        for (int b = 0; b < 3; ++b) K[a][b] = (double)ws->Kmat[pair][3 * a + b];
    {   // subtract M * mu_p mu_g^T
        double mp[3] = { ws->mu_p[p][0], ws->mu_p[p][1], ws->mu_p[p][2] };
        double mg[3] = { ws->mu_g[g][0], ws->mu_g[g][1], ws->mu_g[g][2] };
#pragma unroll
        for (int a = 0; a < 3; ++a)
#pragma unroll
            for (int b = 0; b < 3; ++b)
                K[a][b] -= (double)M_ * mp[a] * mg[b];
    }

    // S = K^T K (symmetric PSD)
    double S[3][3];
#pragma unroll
    for (int a = 0; a < 3; ++a)
#pragma unroll
        for (int b = 0; b < 3; ++b) {
            double acc = 0.0;
#pragma unroll
            for (int c = 0; c < 3; ++c) acc += K[c][a] * K[c][b];
            S[a][b] = acc;
        }

    // Jacobi eigendecomposition S = V Lambda V^T
    double V[3][3] = { {1, 0, 0}, {0, 1, 0}, {0, 0, 1} };
    double tr = S[0][0] + S[1][1] + S[2][2];
    double tol = 1e-26 * tr * tr + 1e-300;
    const int PP[3] = {0, 0, 1};
    const int QQ[3] = {1, 2, 2};
    for (int sweep = 0; sweep < 8; ++sweep) {
        double off = S[0][1] * S[0][1] + S[0][2] * S[0][2] + S[1][2] * S[1][2];
        if (off <= tol) break;
        for (int r3 = 0; r3 < 3; ++r3) {
            int pq = PP[r3], qq = QQ[r3];
            double apq = S[pq][qq];
            if (apq == 0.0) continue;
            double theta = (S[qq][qq] - S[pq][pq]) / (2.0 * apq);
            double tt = copysign(1.0, theta) / (fabs(theta) + sqrt(theta * theta + 1.0));
            double c = 1.0 / sqrt(tt * tt + 1.0);
            double sj = tt * c;
            for (int r = 0; r < 3; ++r) {
                double srp = S[r][pq], srq = S[r][qq];
                S[r][pq] = c * srp - sj * srq;
                S[r][qq] = sj * srp + c * srq;
            }
            for (int cc = 0; cc < 3; ++cc) {
                double spr = S[pq][cc], sqr = S[qq][cc];
                S[pq][cc] = c * spr - sj * sqr;
                S[qq][cc] = sj * spr + c * sqr;
            }
            for (int r = 0; r < 3; ++r) {
                double vrp = V[r][pq], vrq = V[r][qq];
                V[r][pq] = c * vrp - sj * vrq;
                V[r][qq] = sj * vrp + c * vrq;
            }
        }
    }

    // sort eigenpairs descending
    double lam[3] = { S[0][0], S[1][1], S[2][2] };
    int idx[3] = { 0, 1, 2 };
    if (lam[idx[0]] < lam[idx[1]]) { int tt = idx[0]; idx[0] = idx[1]; idx[1] = tt; }
    if (lam[idx[0]] < lam[idx[2]]) { int tt = idx[0]; idx[0] = idx[2]; idx[2] = tt; }
    if (lam[idx[1]] < lam[idx[2]]) { int tt = idx[1]; idx[1] = idx[2]; idx[2] = tt; }
    double Vs[3][3];
    double sv[3];
#pragma unroll
    for (int i = 0; i < 3; ++i) {
        double l = lam[idx[i]];
        sv[i] = sqrt(l > 0.0 ? l : 0.0);
        for (int r = 0; r < 3; ++r) Vs[r][i] = V[r][idx[i]];
    }

    // U columns: u_i = K v_i / s_i
    double U[3][3];
#pragma unroll
    for (int i = 0; i < 3; ++i) {
        double kx = K[0][0] * Vs[0][i] + K[0][1] * Vs[1][i] + K[0][2] * Vs[2][i];
        double ky = K[1][0] * Vs[0][i] + K[1][1] * Vs[1][i] + K[1][2] * Vs[2][i];
        double kz = K[2][0] * Vs[0][i] + K[2][1] * Vs[1][i] + K[2][2] * Vs[2][i];
        double inv = (sv[i] > 1e-12 * sv[0] && sv[i] > 0.0) ? 1.0 / sv[i] : 0.0;
        U[0][i] = kx * inv; U[1][i] = ky * inv; U[2][i] = kz * inv;
    }
    if (sv[2] <= 1e-12 * sv[0] || sv[0] == 0.0) {
        U[0][2] = U[1][0] * U[2][1] - U[2][0] * U[1][1];
        U[1][2] = U[2][0] * U[0][1] - U[0][0] * U[2][1];
        U[2][2] = U[0][0] * U[1][1] - U[1][0] * U[0][1];
    }

    double detK = K[0][0] * (K[1][1] * K[2][2] - K[1][2] * K[2][1])
                - K[0][1] * (K[1][0] * K[2][2] - K[1][2] * K[2][0])
                + K[0][2] * (K[1][0] * K[2][1] - K[1][1] * K[2][0]);
    double d = (detK >= 0.0) ? 1.0 : -1.0;

    double varp = (double)ws->var_p[p];
    double scale = (sv[0] + sv[1] + d * sv[2]) / varp;

    float A[9];
#pragma unroll
    for (int a = 0; a < 3; ++a)
#pragma unroll
        for (int b = 0; b < 3; ++b) {
            double r = Vs[a][0] * U[b][0] + Vs[a][1] * U[b][1] + d * Vs[a][2] * U[b][2];
            A[3 * a + b] = (float)(scale * r);
        }
    double mp[3] = { ws->mu_p[p][0], ws->mu_p[p][1], ws->mu_p[p][2] };
    double mg[3] = { ws->mu_g[g][0], ws->mu_g[g][1], ws->mu_g[g][2] };
    float tvec[3];
#pragma unroll
    for (int a = 0; a < 3; ++a)
        tvec[a] = (float)(mg[a] - ((double)A[3 * a + 0] * mp[0] + (double)A[3 * a + 1] * mp[1] +
                                   (double)A[3 * a + 2] * mp[2]));

#pragma unroll
    for (int j = 0; j < 9; ++j) ws->At[pair][j] = A[j];
#pragma unroll
    for (int j = 0; j < 3; ++j) ws->At[pair][9 + j] = tvec[j];
}

// ---------------- kernel 3: scalar v2v error (2p x 4g) ----------------
// Round-5-proven: A loaded from block-uniform addresses -> compiler keeps the
// 96 floats in SGPRs (VGPR=44, no spill). Scalar fmaf chain, 17 VALU/vert/pair.
__global__ __launch_bounds__(256, 3) void pair_error_r(const float* __restrict__ pred,
                                                       const float* __restrict__ gt,
                                                       WS* __restrict__ ws) {
    int bx = blockIdx.x;
    int gbase = (bx & 63) * 4;
    int pbase = (bx >> 6) * 2;
    int t = threadIdx.x;

    float A[8][12];
#pragma unroll
    for (int gg = 0; gg < 4; ++gg)
#pragma unroll
        for (int pp = 0; pp < 2; ++pp) {
            int pair = (gbase + gg) * P_ + (pbase + pp);
#pragma unroll
            for (int j = 0; j < 12; ++j) A[gg * 2 + pp][j] = ws->At[pair][j];
        }

    const float* pb0 = pred + (size_t)pbase * (M_ * 3);
    const float* pb1 = pred + (size_t)(pbase + 1) * (M_ * 3);
    const float* gb[4];
#pragma unroll
    for (int j = 0; j < 4; ++j) gb[j] = gt + (size_t)(gbase + j) * (M_ * 3);

    float acc[8];
#pragma unroll
    for (int q = 0; q < 8; ++q) acc[q] = 0.f;

    for (int q = t; q < QUADS; q += 256) {
        float px[2][4], py[2][4], pz[2][4];
        LOAD_QUAD(pb0, q, px[0], py[0], pz[0]);
        LOAD_QUAD(pb1, q, px[1], py[1], pz[1]);
#pragma unroll
        for (int gg = 0; gg < 4; ++gg) {
            float gx[4], gy[4], gz[4];
            LOAD_QUAD(gb[gg], q, gx, gy, gz);
#pragma unroll
            for (int pp = 0; pp < 2; ++pp) {
                const float* a = A[gg * 2 + pp];
                float s = 0.f;
#pragma unroll
                for (int k = 0; k < 4; ++k) {
                    float dx = fmaf(a[0], px[pp][k], fmaf(a[1], py[pp][k], fmaf(a[2], pz[pp][k], a[9])))  - gx[k];
                    float dy = fmaf(a[3], px[pp][k], fmaf(a[4], py[pp][k], fmaf(a[5], pz[pp][k], a[10]))) - gy[k];
                    float dz = fmaf(a[6], px[pp][k], fmaf(a[7], py[pp][k], fmaf(a[8], pz[pp][k], a[11]))) - gz[k];
                    s += __builtin_amdgcn_sqrtf(fmaf(dx, dx, fmaf(dy, dy, dz * dz)));
                }
                acc[gg * 2 + pp] += s;
            }
        }
    }

#pragma unroll
    for (int q = 0; q < 8; ++q) {
        float v = acc[q];
        v += __shfl_xor(v, 1);  v += __shfl_xor(v, 2);
        v += __shfl_xor(v, 4);  v += __shfl_xor(v, 8);
        v += __shfl_xor(v, 16); v += __shfl_xor(v, 32);
        acc[q] = v;
    }
    __shared__ float part[4][8];
    int lane = t & 63, wave = t >> 6;
    if (lane == 0) {
#pragma unroll
        for (int q = 0; q < 8; ++q) part[wave][q] = acc[q];
    }
    __syncthreads();
    if (t < 8) {
        float s = part[0][t] + part[1][t] + part[2][t] + part[3][t];
        int gg = t >> 1, pp = t & 1;
        ws->pair_err[(gbase + gg) * P_ + (pbase + pp)] = s / (float)M_;
    }
}

// ---------------- kernel 4: argmin over gallery + write outputs ----------------
__global__ void argmin_out(const WS* __restrict__ ws, float* __restrict__ out) {
    __shared__ float be[8][32];
    __shared__ int   bg[8][32];
    int t = threadIdx.x;
    int p = t & 31, slice = t >> 5;
    float best = 3.4e38f;
    int bi = G_;
    for (int g = slice; g < G_; g += 8) {
        float e = ws->pair_err[g * P_ + p];
        if (e < best) { best = e; bi = g; }
    }
    be[slice][p] = best;
    bg[slice][p] = bi;
    __syncthreads();
    if (t < P_) {
        float b0 = be[0][t];
        int   i0 = bg[0][t];
        for (int s = 1; s < 8; ++s) {
            float e = be[s][t];
            int   i = bg[s][t];
            if (e < b0 || (e == b0 && i < i0)) { b0 = e; i0 = i; }
        }
        out[t] = (float)i0;
        out[P_ + t] = b0;
    }
}

extern "C" void kernel_launch(void* const* d_in, const int* in_sizes, int n_in,
                              void* d_out, int out_size, void* d_ws, size_t ws_size,
                              hipStream_t stream) {
    const float* pred = (const float*)d_in[0];   // (32, 2, 6890, 3)
    const float* gt   = (const float*)d_in[1];   // (256, 2, 6890, 3)
    float* out = (float*)d_out;                  // 64 floats: mapping(32) | min_error(32)
    WS* ws = (WS*)d_ws;                          // ~0.8 MB used

    crosscov_r<<<dim3(NB_CC + P_ + G_), dim3(256), 0, stream>>>(pred, gt, ws);
    pair_svd<<<dim3(NPAIR / 64), dim3(64), 0, stream>>>(ws);
    pair_error_r<<<dim3(16 * 64), dim3(256), 0, stream>>>(pred, gt, ws);
    argmin_out<<<dim3(1), dim3(256), 0, stream>>>(ws, out);
}

// Round 9
// 211.609 us; speedup vs baseline: 1.0972x; 1.0141x over previous
//
#include <hip/hip_runtime.h>
#include <math.h>

#define P_ 32
#define G_ 256
#define NV 6890
#define M_ (2 * NV)          // 13780 joint points per sample
#define QUADS (M_ / 4)       // 3445 vertex-quads (exact)
#define NPAIR (P_ * G_)      // 8192
#define KC 2                 // v-chunks for the pair kernels
#define NB_CC (16 * 64 * KC) // crosscov blocks (2048); stats appended after

// ---------------- workspace layout ----------------
struct WS {
    float mu_p[P_][3];
    float var_p[P_];
    float mu_g[G_][3];
    float At[NPAIR][12];          // A = scale*R (9) then t (3); pair = g*32 + p
    float partK[KC][NPAIR][9];    // per-chunk partial cross-covariance
    float partE[KC][NPAIR];      // per-chunk partial sum of v2v norms
};

// ---------------- block reduction (valid on thread 0) ----------------
__device__ inline double block_reduce(double v, double* smem) {
#pragma unroll
    for (int off = 32; off > 0; off >>= 1) v += __shfl_down(v, off, 64);
    int wid  = threadIdx.x >> 6;
    int lane = threadIdx.x & 63;
    __syncthreads();
    if (lane == 0) smem[wid] = v;
    __syncthreads();
    double r = 0.0;
    if (threadIdx.x == 0) {
        int nw = blockDim.x >> 6;
        for (int w = 0; w < nw; ++w) r += smem[w];
    }
    return r;
}

// load one 4-vertex quad (x[4],y[4],z[4]) from AoS via 3 float4 loads
#define LOAD_QUAD(BASE, Q, X, Y, Z)                                     \
    {                                                                   \
        const float4* _p4 = (const float4*)((BASE) + 12 * (size_t)(Q)); \
        float4 _a = _p4[0], _c = _p4[1], _d = _p4[2];                   \
        X[0] = _a.x; X[1] = _a.w; X[2] = _c.z; X[3] = _d.y;             \
        Y[0] = _a.y; Y[1] = _c.x; Y[2] = _c.w; Y[3] = _d.z;             \
        Z[0] = _a.z; Z[1] = _c.y; Z[2] = _d.x; Z[3] = _d.w;             \
    }

// ---------------- kernel 1: crosscov (2p x 4g, KC chunks) + fused stats -------
// Tile sized so the working set (~125 regs) fits the 170-VGPR budget of
// min-3-waves/EU: round 8 proved the 4x4 tile ALWAYS spills (23 MB scratch).
// blocks 0..2047: kc(2) x ptile(16) x gtile(64); XCD = gtile%8 for L2 locality.
// blocks 2048..2335: per-sample stats (0..31 pred mu/var, 32..287 gt mu).
__global__ __launch_bounds__(256, 3) void crosscov_c(const float* __restrict__ pred,
                                                     const float* __restrict__ gt,
                                                     WS* __restrict__ ws) {
    int bx = blockIdx.x;
    int t = threadIdx.x;

    if (bx >= NB_CC) {
        // ---- stats path ----
        int b = bx - NB_CC;
        bool isP = (b < P_);
        const float* base = isP ? pred + (size_t)b * (M_ * 3)
                                : gt + (size_t)(b - P_) * (M_ * 3);
        double sx = 0, sy = 0, sz = 0, sq = 0;
        for (int q = t; q < QUADS; q += 256) {
            const float4* p4 = (const float4*)(base + 12 * (size_t)q);
            float4 a = p4[0], c = p4[1], d = p4[2];
            sx += (double)a.x + (double)a.w + (double)c.z + (double)d.y;
            sy += (double)a.y + (double)c.x + (double)c.w + (double)d.z;
            sz += (double)a.z + (double)c.y + (double)d.x + (double)d.w;
            if (isP) {
                sq += (double)a.x * a.x + (double)a.y * a.y + (double)a.z * a.z +
                      (double)a.w * a.w + (double)c.x * c.x + (double)c.y * c.y +
                      (double)c.z * c.z + (double)c.w * c.w + (double)d.x * d.x +
                      (double)d.y * d.y + (double)d.z * d.z + (double)d.w * d.w;
            }
        }
        __shared__ double smem[4];
        double rx = block_reduce(sx, smem);
        double ry = block_reduce(sy, smem);
        double rz = block_reduce(sz, smem);
        double rq = block_reduce(sq, smem);
        if (t == 0) {
            double mx = rx / M_, my = ry / M_, mz = rz / M_;
            if (isP) {
                ws->mu_p[b][0] = (float)mx;
                ws->mu_p[b][1] = (float)my;
                ws->mu_p[b][2] = (float)mz;
                ws->var_p[b] = (float)(rq - (mx * mx + my * my + mz * mz) * (double)M_);
            } else {
                ws->mu_g[b - P_][0] = (float)mx;
                ws->mu_g[b - P_][1] = (float)my;
                ws->mu_g[b - P_][2] = (float)mz;
            }
        }
        return;
    }

    // ---- crosscov path ----
    int kc = bx >> 10;
    int rem = bx & 1023;
    int gbase = (rem & 63) * 4;
    int pbase = (rem >> 6) * 2;
    int qbeg = (QUADS * kc) / KC, qend = (QUADS * (kc + 1)) / KC;

    const float* pb0 = pred + (size_t)pbase * (M_ * 3);
    const float* pb1 = pred + (size_t)(pbase + 1) * (M_ * 3);
    const float* gb[4];
#pragma unroll
    for (int j = 0; j < 4; ++j) gb[j] = gt + (size_t)(gbase + j) * (M_ * 3);

    float acc[8][9];
#pragma unroll
    for (int q = 0; q < 8; ++q)
#pragma unroll
        for (int j = 0; j < 9; ++j) acc[q][j] = 0.f;

    for (int q = qbeg + t; q < qend; q += 256) {
        float px[2][4], py[2][4], pz[2][4];
        LOAD_QUAD(pb0, q, px[0], py[0], pz[0]);
        LOAD_QUAD(pb1, q, px[1], py[1], pz[1]);
#pragma unroll
        for (int gg = 0; gg < 4; ++gg) {
            float gx[4], gy[4], gz[4];
            LOAD_QUAD(gb[gg], q, gx, gy, gz);
#pragma unroll
            for (int pp = 0; pp < 2; ++pp) {
                float* a = acc[gg * 2 + pp];
#pragma unroll
                for (int k = 0; k < 4; ++k) {
                    a[0] = fmaf(px[pp][k], gx[k], a[0]);
                    a[1] = fmaf(px[pp][k], gy[k], a[1]);
                    a[2] = fmaf(px[pp][k], gz[k], a[2]);
                    a[3] = fmaf(py[pp][k], gx[k], a[3]);
                    a[4] = fmaf(py[pp][k], gy[k], a[4]);
                    a[5] = fmaf(py[pp][k], gz[k], a[5]);
                    a[6] = fmaf(pz[pp][k], gx[k], a[6]);
                    a[7] = fmaf(pz[pp][k], gy[k], a[7]);
                    a[8] = fmaf(pz[pp][k], gz[k], a[8]);
                }
            }
        }
    }

    // full-wave butterfly -> every lane holds wave total
#pragma unroll
    for (int q = 0; q < 8; ++q)
#pragma unroll
        for (int j = 0; j < 9; ++j) {
            float v = acc[q][j];
            v += __shfl_xor(v, 1);  v += __shfl_xor(v, 2);
            v += __shfl_xor(v, 4);  v += __shfl_xor(v, 8);
            v += __shfl_xor(v, 16); v += __shfl_xor(v, 32);
            acc[q][j] = v;
        }
    __shared__ float part[4][72];
    int lane = t & 63, wave = t >> 6;
    if (lane == 0) {
#pragma unroll
        for (int q = 0; q < 8; ++q)
#pragma unroll
            for (int j = 0; j < 9; ++j) part[wave][q * 9 + j] = acc[q][j];
    }
    __syncthreads();
    if (t < 72) {
        float s = part[0][t] + part[1][t] + part[2][t] + part[3][t];
        int idx = t / 9, j = t % 9;
        int gg = idx >> 1, pp = idx & 1;
        ws->partK[kc][(gbase + gg) * P_ + (pbase + pp)][j] = s;
    }
}

// ---------------- kernel 2: per-pair SVD -> A = scale*R, t ----------------
// block=64 over 128 blocks; Jacobi capped at 8 sweeps (tol breaks ~5), f64.
__global__ __launch_bounds__(64) void pair_svd(WS* ws) {
    int pair = blockIdx.x * blockDim.x + threadIdx.x;
    if (pair >= NPAIR) return;
    int p = pair & 31;
    int g = pair >> 5;

    double K[3][3];
#pragma unroll
    for (int a = 0; a < 3; ++a)
#pragma unroll
        for (int b = 0; b < 3; ++b) {
            double s = 0.0;
#pragma unroll
            for (int kc = 0; kc < KC; ++kc) s += (double)ws->partK[kc][pair][3 * a + b];
            K[a][b] = s;
        }
    {   // subtract M * mu_p mu_g^T
        double mp[3] = { ws->mu_p[p][0], ws->mu_p[p][1], ws->mu_p[p][2] };
        double mg[3] = { ws->mu_g[g][0], ws->mu_g[g][1], ws->mu_g[g][2] };
#pragma unroll
        for (int a = 0; a < 3; ++a)
#pragma unroll
            for (int b = 0; b < 3; ++b)
                K[a][b] -= (double)M_ * mp[a] * mg[b];
    }

    // S = K^T K (symmetric PSD)
    double S[3][3];
#pragma unroll
    for (int a = 0; a < 3; ++a)
#pragma unroll
        for (int b = 0; b < 3; ++b) {
            double acc = 0.0;
#pragma unroll
            for (int c = 0; c < 3; ++c) acc += K[c][a] * K[c][b];
            S[a][b] = acc;
        }

    // Jacobi eigendecomposition S = V Lambda V^T
    double V[3][3] = { {1, 0, 0}, {0, 1, 0}, {0, 0, 1} };
    double tr = S[0][0] + S[1][1] + S[2][2];
    double tol = 1e-26 * tr * tr + 1e-300;
    const int PP[3] = {0, 0, 1};
    const int QQ[3] = {1, 2, 2};
    for (int sweep = 0; sweep < 8; ++sweep) {
        double off = S[0][1] * S[0][1] + S[0][2] * S[0][2] + S[1][2] * S[1][2];
        if (off <= tol) break;
        for (int r3 = 0; r3 < 3; ++r3) {
            int pq = PP[r3], qq = QQ[r3];
            double apq = S[pq][qq];
            if (apq == 0.0) continue;
            double theta = (S[qq][qq] - S[pq][pq]) / (2.0 * apq);
            double tt = copysign(1.0, theta) / (fabs(theta) + sqrt(theta * theta + 1.0));
            double c = 1.0 / sqrt(tt * tt + 1.0);
            double sj = tt * c;
            for (int r = 0; r < 3; ++r) {
                double srp = S[r][pq], srq = S[r][qq];
                S[r][pq] = c * srp - sj * srq;
                S[r][qq] = sj * srp + c * srq;
            }
            for (int cc = 0; cc < 3; ++cc) {
                double spr = S[pq][cc], sqr = S[qq][cc];
                S[pq][cc] = c * spr - sj * sqr;
                S[qq][cc] = sj * spr + c * sqr;
            }
            for (int r = 0; r < 3; ++r) {
                double vrp = V[r][pq], vrq = V[r][qq];
                V[r][pq] = c * vrp - sj * vrq;
                V[r][qq] = sj * vrp + c * vrq;
            }
        }
    }

    // sort eigenpairs descending
    double lam[3] = { S[0][0], S[1][1], S[2][2] };
    int idx[3] = { 0, 1, 2 };
    if (lam[idx[0]] < lam[idx[1]]) { int tt = idx[0]; idx[0] = idx[1]; idx[1] = tt; }
    if (lam[idx[0]] < lam[idx[2]]) { int tt = idx[0]; idx[0] = idx[2]; idx[2] = tt; }
    if (lam[idx[1]] < lam[idx[2]]) { int tt = idx[1]; idx[1] = idx[2]; idx[2] = tt; }
    double Vs[3][3];
    double sv[3];
#pragma unroll
    for (int i = 0; i < 3; ++i) {
        double l = lam[idx[i]];
        sv[i] = sqrt(l > 0.0 ? l : 0.0);
        for (int r = 0; r < 3; ++r) Vs[r][i] = V[r][idx[i]];
    }

    // U columns: u_i = K v_i / s_i
    double U[3][3];
#pragma unroll
    for (int i = 0; i < 3; ++i) {
        double kx = K[0][0] * Vs[0][i] + K[0][1] * Vs[1][i] + K[0][2] * Vs[2][i];
        double ky = K[1][0] * Vs[0][i] + K[1][1] * Vs[1][i] + K[1][2] * Vs[2][i];
        double kz = K[2][0] * Vs[0][i] + K[2][1] * Vs[1][i] + K[2][2] * Vs[2][i];
        double inv = (sv[i] > 1e-12 * sv[0] && sv[i] > 0.0) ? 1.0 / sv[i] : 0.0;
        U[0][i] = kx * inv; U[1][i] = ky * inv; U[2][i] = kz * inv;
    }
    if (sv[2] <= 1e-12 * sv[0] || sv[0] == 0.0) {
        U[0][2] = U[1][0] * U[2][1] - U[2][0] * U[1][1];
        U[1][2] = U[2][0] * U[0][1] - U[0][0] * U[2][1];
        U[2][2] = U[0][0] * U[1][1] - U[1][0] * U[0][1];
    }

    double detK = K[0][0] * (K[1][1] * K[2][2] - K[1][2] * K[2][1])
                - K[0][1] * (K[1][0] * K[2][2] - K[1][2] * K[2][0])
                + K[0][2] * (K[1][0] * K[2][1] - K[1][1] * K[2][0]);
    double d = (detK >= 0.0) ? 1.0 : -1.0;

    double varp = (double)ws->var_p[p];
    double scale = (sv[0] + sv[1] + d * sv[2]) / varp;

    float A[9];
#pragma unroll
    for (int a = 0; a < 3; ++a)
#pragma unroll
        for (int b = 0; b < 3; ++b) {
            double r = Vs[a][0] * U[b][0] + Vs[a][1] * U[b][1] + d * Vs[a][2] * U[b][2];
            A[3 * a + b] = (float)(scale * r);
        }
    double mp[3] = { ws->mu_p[p][0], ws->mu_p[p][1], ws->mu_p[p][2] };
    double mg[3] = { ws->mu_g[g][0], ws->mu_g[g][1], ws->mu_g[g][2] };
    float tvec[3];
#pragma unroll
    for (int a = 0; a < 3; ++a)
        tvec[a] = (float)(mg[a] - ((double)A[3 * a + 0] * mp[0] + (double)A[3 * a + 1] * mp[1] +
                                   (double)A[3 * a + 2] * mp[2]));

#pragma unroll
    for (int j = 0; j < 9; ++j) ws->At[pair][j] = A[j];
#pragma unroll
    for (int j = 0; j < 3; ++j) ws->At[pair][9 + j] = tvec[j];
}

// ---------------- kernel 3: scalar v2v error (2p x 4g, KC chunks) ----------------
// A loaded from block-uniform addresses -> SGPR-resident (VGPR=44, no spill).
// KC=2 v-split doubles blocks to 2048 for occupancy/load-balance.
__global__ __launch_bounds__(256, 3) void pair_error_c(const float* __restrict__ pred,
                                                       const float* __restrict__ gt,
                                                       WS* __restrict__ ws) {
    int bx = blockIdx.x;
    int kc = bx >> 10;
    int rem = bx & 1023;
    int gbase = (rem & 63) * 4;
    int pbase = (rem >> 6) * 2;
    int qbeg = (QUADS * kc) / KC, qend = (QUADS * (kc + 1)) / KC;
    int t = threadIdx.x;

    float A[8][12];
#pragma unroll
    for (int gg = 0; gg < 4; ++gg)
#pragma unroll
        for (int pp = 0; pp < 2; ++pp) {
            int pair = (gbase + gg) * P_ + (pbase + pp);
#pragma unroll
            for (int j = 0; j < 12; ++j) A[gg * 2 + pp][j] = ws->At[pair][j];
        }

    const float* pb0 = pred + (size_t)pbase * (M_ * 3);
    const float* pb1 = pred + (size_t)(pbase + 1) * (M_ * 3);
    const float* gb[4];
#pragma unroll
    for (int j = 0; j < 4; ++j) gb[j] = gt + (size_t)(gbase + j) * (M_ * 3);

    float acc[8];
#pragma unroll
    for (int q = 0; q < 8; ++q) acc[q] = 0.f;

    for (int q = qbeg + t; q < qend; q += 256) {
        float px[2][4], py[2][4], pz[2][4];
        LOAD_QUAD(pb0, q, px[0], py[0], pz[0]);
        LOAD_QUAD(pb1, q, px[1], py[1], pz[1]);
#pragma unroll
        for (int gg = 0; gg < 4; ++gg) {
            float gx[4], gy[4], gz[4];
            LOAD_QUAD(gb[gg], q, gx, gy, gz);
#pragma unroll
            for (int pp = 0; pp < 2; ++pp) {
                const float* a = A[gg * 2 + pp];
                float s = 0.f;
#pragma unroll
                for (int k = 0; k < 4; ++k) {
                    float dx = fmaf(a[0], px[pp][k], fmaf(a[1], py[pp][k], fmaf(a[2], pz[pp][k], a[9])))  - gx[k];
                    float dy = fmaf(a[3], px[pp][k], fmaf(a[4], py[pp][k], fmaf(a[5], pz[pp][k], a[10]))) - gy[k];
                    float dz = fmaf(a[6], px[pp][k], fmaf(a[7], py[pp][k], fmaf(a[8], pz[pp][k], a[11]))) - gz[k];
                    s += __builtin_amdgcn_sqrtf(fmaf(dx, dx, fmaf(dy, dy, dz * dz)));
                }
                acc[gg * 2 + pp] += s;
            }
        }
    }

#pragma unroll
    for (int q = 0; q < 8; ++q) {
        float v = acc[q];
        v += __shfl_xor(v, 1);  v += __shfl_xor(v, 2);
        v += __shfl_xor(v, 4);  v += __shfl_xor(v, 8);
        v += __shfl_xor(v, 16); v += __shfl_xor(v, 32);
        acc[q] = v;
    }
    __shared__ float part[4][8];
    int lane = t & 63, wave = t >> 6;
    if (lane == 0) {
#pragma unroll
        for (int q = 0; q < 8; ++q) part[wave][q] = acc[q];
    }
    __syncthreads();
    if (t < 8) {
        float s = part[0][t] + part[1][t] + part[2][t] + part[3][t];
        int gg = t >> 1, pp = t & 1;
        ws->partE[kc][(gbase + gg) * P_ + (pbase + pp)] = s;
    }
}

// ---------------- kernel 4: argmin over gallery + write outputs ----------------
__global__ void argmin_out(const WS* __restrict__ ws, float* __restrict__ out) {
    __shared__ float be[8][32];
    __shared__ int   bg[8][32];
    int t = threadIdx.x;
    int p = t & 31, slice = t >> 5;
    float best = 3.4e38f;
    int bi = G_;
    for (int g = slice; g < G_; g += 8) {
        double s = 0.0;
#pragma unroll
        for (int kc = 0; kc < KC; ++kc) s += (double)ws->partE[kc][g * P_ + p];
        float e = (float)(s / (double)M_);
        if (e < best) { best = e; bi = g; }
    }
    be[slice][p] = best;
    bg[slice][p] = bi;
    __syncthreads();
    if (t < P_) {
        float b0 = be[0][t];
        int   i0 = bg[0][t];
        for (int s = 1; s < 8; ++s) {
            float e = be[s][t];
            int   i = bg[s][t];
            if (e < b0 || (e == b0 && i < i0)) { b0 = e; i0 = i; }
        }
        out[t] = (float)i0;
        out[P_ + t] = b0;
    }
}

extern "C" void kernel_launch(void* const* d_in, const int* in_sizes, int n_in,
                              void* d_out, int out_size, void* d_ws, size_t ws_size,
                              hipStream_t stream) {
    const float* pred = (const float*)d_in[0];   // (32, 2, 6890, 3)
    const float* gt   = (const float*)d_in[1];   // (256, 2, 6890, 3)
    float* out = (float*)d_out;                  // 64 floats: mapping(32) | min_error(32)
    WS* ws = (WS*)d_ws;                          // ~1.1 MB used

    crosscov_c<<<dim3(NB_CC + P_ + G_), dim3(256), 0, stream>>>(pred, gt, ws);
    pair_svd<<<dim3(NPAIR / 64), dim3(64), 0, stream>>>(ws);
    pair_error_c<<<dim3(16 * 64 * KC), dim3(256), 0, stream>>>(pred, gt, ws);
    argmin_out<<<dim3(1), dim3(256), 0, stream>>>(ws, out);
}